// Round 2
// baseline (6182.148 us; speedup 1.0000x reference)
//
#include <hip/hip_runtime.h>
#include <stdint.h>

// ---------------------------------------------------------------------------
// Fused spiking-MLP forward: 20 timesteps, B=16384, 784 -> 400 -> 10.
//
// RNG: jax threefry with PARTITIONABLE semantics (modern default):
//   split(key(42),20) [foldlike]: key_t = (x0,x1) = TF((0,42), (0, t)).
//   random_bits 32-bit [partitionable]: element e (row-major flat index):
//     (x0,x1) = TF(key_t, (0, e));  bits = x0 ^ x1.          <-- HYPOTHESIS
//     u = bitcast((bits>>9)|0x3f800000) - 1.0f;  xi = (x > u).
//   (Round-1 disproved ORIGINAL semantics: absmax 0.648 = decorrelated.)
//   Fallbacks if this fails ~0.65: bits = x1 (trunc), then bits = x0 (shr32).
//
// Membrane state & dots in fp64: spike thresholds (mem>0.5) are knife-edge;
// fp32 jitter (~1e-6) would flip ~100 spikes vs the np-f64 reference. fp64
// sequential accumulation differs from np dot by ~1e-13 -> ~0 flips.
//
// Layout: 1024 blocks x 256 threads. Block g owns 16 samples (rows g*8..+7
// and +8192). Wave sg owns samples 4sg..4sg+3; xi bits are wave-uniform ->
// scalar branch skips ~50% of fp64 adds. Thread covers neurons j = lane+64k.
// ---------------------------------------------------------------------------

#define BSZ    16384
#define INDIM  784
#define HID    400
#define ODIM   10
#define TSTEPS 20

#define TD   16           // d-tile size
#define NT   49           // 784/16 tiles
#define WTJ  448          // padded neuron rows in LDS tile
#define XIW  26           // xi words per sample (784 bits -> 25, +1 pad)
#define SPW  14           // spike words per sample (448 bits)

__device__ __forceinline__ void tfr(uint32_t& x0, uint32_t& x1, int r) {
  x0 += x1;
  x1 = (x1 << r) | (x1 >> (32 - r));
  x1 ^= x0;
}

__device__ __forceinline__ uint2 tf2x32(uint32_t k0, uint32_t k1,
                                        uint32_t c0, uint32_t c1) {
  uint32_t k2 = k0 ^ k1 ^ 0x1BD11BDAu;
  uint32_t x0 = c0 + k0, x1 = c1 + k1;
  tfr(x0,x1,13); tfr(x0,x1,15); tfr(x0,x1,26); tfr(x0,x1,6);
  x0 += k1; x1 += k2 + 1u;
  tfr(x0,x1,17); tfr(x0,x1,29); tfr(x0,x1,16); tfr(x0,x1,24);
  x0 += k2; x1 += k0 + 2u;
  tfr(x0,x1,13); tfr(x0,x1,15); tfr(x0,x1,26); tfr(x0,x1,6);
  x0 += k0; x1 += k1 + 3u;
  tfr(x0,x1,17); tfr(x0,x1,29); tfr(x0,x1,16); tfr(x0,x1,24);
  x0 += k1; x1 += k2 + 4u;
  tfr(x0,x1,13); tfr(x0,x1,15); tfr(x0,x1,26); tfr(x0,x1,6);
  x0 += k2; x1 += k0 + 5u;
  return make_uint2(x0, x1);
}

__device__ __forceinline__ float bits_to_unif(uint32_t b) {
  return __uint_as_float((b >> 9) | 0x3f800000u) - 1.0f;
}

__global__ __launch_bounds__(256, 4)
void snn_fused(const float* __restrict__ x,  const float* __restrict__ W1,
               const float* __restrict__ b1, const float* __restrict__ W2,
               const float* __restrict__ b2, float* __restrict__ out) {
  __shared__ float    wt[TD * WTJ];      // 28672 B, layout [dt][j]
  __shared__ uint32_t xib[16][XIW];      // 1664 B
  __shared__ uint32_t spk[16][SPW];      // 896 B

  const int tid  = threadIdx.x;
  const int g    = blockIdx.x;           // 0..1023
  const int sg   = tid >> 6;             // wave id = sample group
  const int lane = tid & 63;             // also the neuron-thread index

  // persistent per-thread layer-1 state: mem1[s][k] for samples 4sg+s,
  // neurons j = lane + 64k (j>=400 are zero-padded dummies)
  double   mem1[4][7];
  uint32_t spv[4];                       // prev-step spike bits (bit k)
#pragma unroll
  for (int s = 0; s < 4; ++s) {
    spv[s] = 0u;
#pragma unroll
    for (int k = 0; k < 7; ++k) mem1[s][k] = 0.0;
  }

  // layer-2 ownership: tid<160 -> (sample ls, output lo)
  const int ls = tid / ODIM;             // valid when tid<160
  const int lo = tid - ls * ODIM;
  double m2 = 0.0;
  int    s2 = 0;
  int    cnt2 = 0;
  double b2r = (tid < 160) ? (double)b2[lo] : 0.0;

  for (int t = 0; t < TSTEPS; ++t) {
    // ---- step key: foldlike split -> key_t = TF((0,42), (0,t)) ----
    const uint2 kt = tf2x32(0u, 42u, 0u, (uint32_t)t);
    const uint32_t kt0 = kt.x, kt1 = kt.y;

    __syncthreads();   // prev step's LDS readers (tiles, spikes) all done

    // ---- xi generation: wave sg produces its own samples 4sg..4sg+3 ----
#pragma unroll
    for (int s = 0; s < 4; ++s) {
      const int q   = 4 * sg + s;            // block-sample index 0..15
      const int row = g * 8 + (q & 7) + ((q >= 8) ? 8192 : 0);
      for (int c = 0; c < 13; ++c) {
        const int d = c * 64 + lane;
        int xb = 0;
        if (d < INDIM) {
          const uint32_t e = (uint32_t)row * (uint32_t)INDIM + (uint32_t)d;
          uint2 r = tf2x32(kt0, kt1, 0u, e);     // counter = (hi,lo) of e
          const uint32_t bits = r.x ^ r.y;       // partitionable 32b combine
          xb = x[row * INDIM + d] > bits_to_unif(bits);
        }
        unsigned long long m = __ballot(xb);
        if (lane == 0) {
          xib[q][2*c]     = (uint32_t)m;
          xib[q][2*c + 1] = (uint32_t)(m >> 32);
        }
      }
    }

    // ---- decay + reset into accumulator (ref: mem*0.2*(1-spike)) ----
#pragma unroll
    for (int s = 0; s < 4; ++s)
#pragma unroll
      for (int k = 0; k < 7; ++k)
        mem1[s][k] = ((spv[s] >> k) & 1u) ? 0.0 : mem1[s][k] * 0.2;

    // ---- layer 1: accumulate xi @ W1^T over 49 LDS-staged d-tiles ----
    for (int td = 0; td < NT; ++td) {
      const int d0 = td * TD;
      __syncthreads();                       // prev tile consumed
      // stage W1[0:448][d0:d0+16] into wt[dt][j] (zero-pad j>=400)
      for (int jj = tid; jj < WTJ; jj += 256) {
        float v[16];
        if (jj < HID) {
          const float4* src = (const float4*)(W1 + jj * INDIM + d0);
          float4 a = src[0], b = src[1], c = src[2], dd = src[3];
          v[0]=a.x; v[1]=a.y; v[2]=a.z; v[3]=a.w;
          v[4]=b.x; v[5]=b.y; v[6]=b.z; v[7]=b.w;
          v[8]=c.x; v[9]=c.y; v[10]=c.z; v[11]=c.w;
          v[12]=dd.x; v[13]=dd.y; v[14]=dd.z; v[15]=dd.w;
        } else {
#pragma unroll
          for (int q = 0; q < 16; ++q) v[q] = 0.0f;
        }
#pragma unroll
        for (int dt = 0; dt < TD; ++dt) wt[dt * WTJ + jj] = v[dt];
      }
      __syncthreads();

      // xi bits for this tile (wave-uniform per sample group)
      const int wi = d0 >> 5;
      const int sh = d0 & 31;                // 0 or 16
      uint32_t xw[4];
#pragma unroll
      for (int s = 0; s < 4; ++s)
        xw[s] = (xib[4*sg + s][wi] >> sh) & 0xFFFFu;

#pragma unroll 4
      for (int dt = 0; dt < TD; ++dt) {
        double wd[7];
#pragma unroll
        for (int k = 0; k < 7; ++k)
          wd[k] = (double)wt[dt * WTJ + lane + 64 * k];
#pragma unroll
        for (int s = 0; s < 4; ++s) {
          // xi bit is identical for all lanes in this wave -> scalar branch
          if (__builtin_amdgcn_readfirstlane((xw[s] >> dt) & 1u)) {
#pragma unroll
            for (int k = 0; k < 7; ++k) mem1[s][k] += wd[k];
          }
        }
      }
    }

    // ---- finalize layer 1: + b1, threshold, pack spikes ----
#pragma unroll
    for (int s = 0; s < 4; ++s) {
      uint32_t m = 0u;
#pragma unroll
      for (int k = 0; k < 7; ++k) {
        const int j = lane + 64 * k;
        const double bb = (j < HID) ? (double)b1[j] : 0.0;
        mem1[s][k] += bb;
        if (mem1[s][k] > 0.5) m |= (1u << k);   // j>=400 stays <=0, never fires
      }
      spv[s] = m;
#pragma unroll
      for (int k = 0; k < 7; ++k) {
        unsigned long long bm = __ballot((m >> k) & 1u);
        if (lane == 0) {
          spk[4*sg + s][2*k]     = (uint32_t)bm;
          spk[4*sg + s][2*k + 1] = (uint32_t)(bm >> 32);
        }
      }
    }
    __syncthreads();                         // spikes visible

    // ---- layer 2: 160 threads, bit-sparse fp64 dot over W2 rows ----
    if (tid < 160) {
      double a2  = s2 ? 0.0 : m2 * 0.2;
      double dot = 0.0;
      for (int w = 0; w < 13; ++w) {
        uint32_t bits = spk[ls][w];
        if (w == 12) bits &= 0xFFFFu;        // j in [384,400)
        const int jb = 32 * w;
        while (bits) {
          const int bi = __ffs(bits) - 1;
          bits &= bits - 1u;
          dot += (double)W2[lo * HID + jb + bi];
        }
      }
      m2 = (a2 + dot) + b2r;
      s2 = (m2 > 0.5) ? 1 : 0;
      cnt2 += s2;
    }
  }

  // ---- output: h2_sum / 20 ----
  if (tid < 160) {
    const int row = g * 8 + (ls & 7) + ((ls >= 8) ? 8192 : 0);
    out[row * ODIM + lo] = (float)((double)cnt2 / 20.0);
  }
}

extern "C" void kernel_launch(void* const* d_in, const int* in_sizes, int n_in,
                              void* d_out, int out_size, void* d_ws, size_t ws_size,
                              hipStream_t stream) {
  const float* x  = (const float*)d_in[0];
  const float* W1 = (const float*)d_in[1];
  const float* b1 = (const float*)d_in[2];
  const float* W2 = (const float*)d_in[3];
  const float* b2 = (const float*)d_in[4];
  // d_in[5] = time_window (int, ==20) — compile-time constant here.
  float* out = (float*)d_out;
  hipLaunchKernelGGL(snn_fused, dim3(1024), dim3(256), 0, stream,
                     x, W1, b1, W2, b2, out);
}